// Round 9
// baseline (399.200 us; speedup 1.0000x reference)
//
#include <hip/hip_runtime.h>
#include <math.h>

#define BS 8
#define NQ 1200
#define NV 19560
#define NVP 19584               // padded pix stride for v_b (= TPB*128)
#define EMB 256
#define TPB 153                 // 128-row tiles per batch

typedef __bf16 bf16;
typedef bf16 bf16x8 __attribute__((ext_vector_type(8)));
typedef bf16 bf16x4 __attribute__((ext_vector_type(4)));
typedef float f32x4 __attribute__((ext_vector_type(4)));

static __device__ __forceinline__ bf16x8 cvt8(float4 a, float4 b) {
    bf16x8 r;
    r[0] = (bf16)a.x; r[1] = (bf16)a.y; r[2] = (bf16)a.z; r[3] = (bf16)a.w;
    r[4] = (bf16)b.x; r[5] = (bf16)b.y; r[6] = (bf16)b.z; r[7] = (bf16)b.w;
    return r;
}

// async 16B global -> LDS (wave-uniform LDS base + lane*16 in HW; global src per-lane)
static __device__ __forceinline__ void gl16(const void* g, void* l) {
    __builtin_amdgcn_global_load_lds(
        (const __attribute__((address_space(1))) void*)g,
        (__attribute__((address_space(3))) void*)l, 16, 0, 0);
}

// Prep v2: weight packs via LDS 64x64 tile-transpose (coalesced reads AND
// writes; old version read 4B per 1KB-stride line). qsum via float4. Plus
// combined bias cb[384] = bo(256) || ba(128).
// Grid: 56 transpose tiles + 1200 qsum blocks + 1 bias block = 1257.
__global__ __launch_bounds__(256) void prep_k(
    const float* __restrict__ Wv, const float* __restrict__ Wo,
    const float* __restrict__ Wa, const float* __restrict__ Wout,
    const float* __restrict__ query, const float* __restrict__ qpos,
    const float* __restrict__ bo, const float* __restrict__ ba,
    bf16* __restrict__ Wv_p, bf16* __restrict__ Wo_p,
    bf16* __restrict__ Wa_p, bf16* __restrict__ Wout_p,
    bf16* __restrict__ qsum, float* __restrict__ cb)
{
    __shared__ float t64[64][65];
    int bid = blockIdx.x, tid = threadIdx.x;
    if (bid < 56) {
        const float* src; bf16* dst; int N, tile;
        if (bid < 16)      { src = Wv;   dst = Wv_p;   N = 256; tile = bid; }
        else if (bid < 32) { src = Wo;   dst = Wo_p;   N = 256; tile = bid - 16; }
        else if (bid < 40) { src = Wa;   dst = Wa_p;   N = 128; tile = bid - 32; }
        else               { src = Wout; dst = Wout_p; N = 256; tile = bid - 40; }
        int ntn = N >> 6;
        int k0 = (tile / ntn) << 6, n0 = (tile % ntn) << 6;
#pragma unroll
        for (int j = 0; j < 16; ++j) {
            int idx = j * 256 + tid;
            int r = idx >> 6, c = idx & 63;
            t64[r][c] = src[(size_t)(k0 + r) * N + n0 + c];
        }
        __syncthreads();
#pragma unroll
        for (int j = 0; j < 16; ++j) {
            int idx = j * 256 + tid;
            int rn = idx >> 6, ck = idx & 63;
            dst[(size_t)(n0 + rn) * 256 + k0 + ck] = (bf16)t64[ck][rn];
        }
    } else if (bid < 1256) {
        size_t base = (size_t)(bid - 56) * 2048 + tid * 8;
        float4 a0 = *(const float4*)(query + base);
        float4 a1 = *(const float4*)(query + base + 4);
        float4 b0 = *(const float4*)(qpos + base);
        float4 b1 = *(const float4*)(qpos + base + 4);
        bf16x8 o;
        o[0] = (bf16)(a0.x + b0.x); o[1] = (bf16)(a0.y + b0.y);
        o[2] = (bf16)(a0.z + b0.z); o[3] = (bf16)(a0.w + b0.w);
        o[4] = (bf16)(a1.x + b1.x); o[5] = (bf16)(a1.y + b1.y);
        o[6] = (bf16)(a1.z + b1.z); o[7] = (bf16)(a1.w + b1.w);
        *(bf16x8*)(qsum + base) = o;
    } else {
        cb[tid] = bo[tid];
        if (tid < 128) cb[256 + tid] = ba[tid];
    }
}

// v-GEMM v12 (R2-hybrid): v[b][h][pix(NVP)][32] = bf16(value @ Wv + bv).
// High-concurrency x 1x-traffic quadrant: 128-row tile per block (1224
// blocks), barrier-per-chunk double buffering of BOTH A and B K=32 chunks
// (LDS 64KB -> 2 blocks/CU, 8 waves: while one block drains vmcnt at its
// barrier, the co-resident block computes -- R2's measured 8.9 B/cyc/CU
// mechanism, now with B-chunk traffic halved vs R2 by the bigger tile).
// B re-staged per chunk from L2 (B=128KB, L2-hot). Swapped-operand epilogue
// (R8-proven): packed bf16x4 stores, bias folded into acc init, unguarded
// stores into padded NVP.
// Swizzles (pre-swizzled GLOBAL src; LDS dest linear as gl16 requires):
//   A: slot s of row r holds global slot s^(r&7)      (8x16B slots/row)
//   B: slot s of col c holds global slot s^((c^(c>>2))&3) (4x16B slots/col)
__global__ __launch_bounds__(256, 2) void vgemm_k(
    const float* __restrict__ A, const bf16* __restrict__ Bp,
    const float* __restrict__ bias, bf16* __restrict__ outB)
{
    __shared__ __align__(16) float sA[2][128 * 32];   // 2 x 16 KB
    __shared__ __align__(16) bf16  sB[2][256 * 32];   // 2 x 16 KB
    const int tid = threadIdx.x;
    const int lane = tid & 63;
    const int w = tid >> 6;
    const int l16 = lane & 15;
    const int qd = lane >> 4;
    const int t = blockIdx.x;
    const int b = t / TPB, p0 = (t - b * TPB) * 128;

    // A chunk stage: 128 rows x 32 f32; wave w rows w*32..+31 via 4 gl16 of 8 rows.
    const int arow = lane >> 3;                 // row within 8-group
    const int aslot = lane & 7;
    auto stageA = [&](int kg, int buf) {
#pragma unroll
        for (int i = 0; i < 4; ++i) {
            int lr = w * 32 + i * 8 + arow;     // local row; lr&7 == arow
            int pix = min(p0 + lr, NV - 1);
            int gs = aslot ^ arow;
            gl16(A + ((size_t)b * NV + pix) * 256 + kg * 32 + gs * 4,
                 (float*)sA[buf] + (w * 32 + i * 8) * 32);
        }
    };
    // B chunk stage: 256 cols x 32 bf16 (64B/col); wave w cols w*64..+63 via 4 gl16.
    const int bcol = lane >> 2;                 // col within 16-group
    const int bslt = lane & 3;
    auto stageB = [&](int kg, int buf) {
#pragma unroll
        for (int i = 0; i < 4; ++i) {
            int c = w * 64 + i * 16 + bcol;
            int key = (c ^ (c >> 2)) & 3;
            gl16(Bp + (size_t)c * 256 + kg * 32 + (bslt ^ key) * 8,
                 (bf16*)sB[buf] + (w * 64 + i * 16) * 32);
        }
    };

    stageA(0, 0);
    stageB(0, 0);

    // bias folded into acc init: channels ct*16 + qd*4 .. +3
    f32x4 acc0[16], acc1[16];
#pragma unroll
    for (int ct = 0; ct < 16; ++ct) {
        f32x4 bb = *(const f32x4*)(bias + ct * 16 + qd * 4);
        acc0[ct] = bb; acc1[ct] = bb;
    }

    __syncthreads();   // chunk 0 landed (compiler drains vmcnt before barrier)

    const int akey = l16 & 7;
    int buf = 0;
#pragma unroll
    for (int kc = 0; kc < 8; ++kc) {
        if (kc < 7) { stageA(kc + 1, buf ^ 1); stageB(kc + 1, buf ^ 1); }
        // compute chunk kc from sA/sB[buf]
        {
            const float* ar0 = sA[buf] + (w * 32 + l16) * 32;
            const float* ar1 = ar0 + 16 * 32;
            float4 a00 = *(const float4*)(ar0 + ((qd * 2    ) ^ akey) * 4);
            float4 a01 = *(const float4*)(ar0 + ((qd * 2 + 1) ^ akey) * 4);
            float4 a10 = *(const float4*)(ar1 + ((qd * 2    ) ^ akey) * 4);
            float4 a11 = *(const float4*)(ar1 + ((qd * 2 + 1) ^ akey) * 4);
            bf16x8 af0 = cvt8(a00, a01);
            bf16x8 af1 = cvt8(a10, a11);
#pragma unroll
            for (int ct = 0; ct < 16; ++ct) {
                int c = ct * 16 + l16;
                int key = (c ^ (c >> 2)) & 3;
                bf16x8 bfr = *(const bf16x8*)(sB[buf] + (size_t)c * 32 + (qd ^ key) * 8);
                // swapped operands: D[m=channel][n=pix]
                acc0[ct] = __builtin_amdgcn_mfma_f32_16x16x32_bf16(bfr, af0, acc0[ct], 0, 0, 0);
                acc1[ct] = __builtin_amdgcn_mfma_f32_16x16x32_bf16(bfr, af1, acc1[ct], 0, 0, 0);
            }
        }
        __syncthreads();   // next chunk landed; safe to swap
        buf ^= 1;
    }

    // epilogue: lane (qd,l16) holds channels ct*16+qd*4..+3 of pix p0+w*32+l16 (+16).
    // 32 x 8B packed stores into padded [b][h][NVP][32] (unguarded).
    int pix0 = p0 + w * 32 + l16;
#pragma unroll
    for (int ct = 0; ct < 16; ++ct) {
        bf16* dst = outB + ((size_t)(b * 8 + (ct >> 1)) * NVP) * 32
                         + (ct & 1) * 16 + qd * 4;
        bf16x4 v0, v1;
#pragma unroll
        for (int r = 0; r < 4; ++r) { v0[r] = (bf16)acc0[ct][r]; v1[r] = (bf16)acc1[ct][r]; }
        *(bf16x4*)(dst + (size_t)pix0 * 32)        = v0;
        *(bf16x4*)(dst + (size_t)(pix0 + 16) * 32) = v1;
    }
}

// Small GEMM (M=9600): C = bf16A @ Bp^T (+bias)(+res). K=256. NGRP column
// groups of NB, B group in LDS staged once, A direct-to-reg 2-tile pipeline.
template <int NS, int NB, int NGRP, bool HAS_RES, bool OUT_BF16>
__global__ __launch_bounds__(256, 2) void gemm3_k(
    const bf16* __restrict__ Ah, const bf16* __restrict__ Bp,
    const float* __restrict__ bias, const float* __restrict__ res,
    float* __restrict__ outF, bf16* __restrict__ outB, int Mtiles)
{
    constexpr int CT = NB / 16;
    __shared__ __align__(16) bf16 sB[NB * 256];
    const int tid = threadIdx.x;
    const int lane = tid & 63;
    const int w = tid >> 6;
    const int l16 = lane & 15;
    const int qd = lane >> 4;
    const int col0 = (blockIdx.x % NGRP) * NB;
    const int tstride = gridDim.x / NGRP;
    const bf16* Bsrc = Bp + (size_t)col0 * 256;

    uint4 curH[8], nxtH[8];
    auto loadA = [&](int t, uint4* dH) {
        size_t rb = ((size_t)t * 64 + w * 16 + l16) * 256;
#pragma unroll
        for (int kc = 0; kc < 8; ++kc)
            dH[kc] = *(const uint4*)(Ah + rb + kc * 32 + qd * 8);
    };

    int tile = blockIdx.x / NGRP;
    if (tile < Mtiles) loadA(tile, curH);

#pragma unroll
    for (int i = 0; i < NB * 32 / 256; ++i) {
        int s = i * 256 + tid;
        int r = s >> 5, p = s & 31, c = p ^ (r & 7);
        gl16(Bsrc + (size_t)r * 256 + c * 8, sB + (size_t)(i * 256 + w * 64) * 8);
    }
    __syncthreads();

    for (; tile < Mtiles; tile += tstride) {
        int nt = tile + tstride;
        if (nt < Mtiles) loadA(nt, nxtH);

        f32x4 acc[CT];
#pragma unroll
        for (int c = 0; c < CT; ++c) acc[c] = (f32x4){0.f, 0.f, 0.f, 0.f};
#pragma unroll
        for (int kc = 0; kc < 8; ++kc) {
            bf16x8 af = *(const bf16x8*)&curH[kc];
#pragma unroll
            for (int ct = 0; ct < CT; ++ct) {
                int brow = ct * 16 + l16;
                int chunk = (kc * 4 + qd) ^ (l16 & 7);
                bf16x8 bfr = *(const bf16x8*)(sB + (size_t)brow * 256 + chunk * 8);
                acc[ct] = __builtin_amdgcn_mfma_f32_16x16x32_bf16(af, bfr, acc[ct], 0, 0, 0);
            }
        }
#pragma unroll
        for (int ct = 0; ct < CT; ++ct) {
            int col = col0 + ct * 16 + l16;
            float bbv = bias[col];
#pragma unroll
            for (int r = 0; r < 4; ++r) {
                int row = tile * 64 + w * 16 + qd * 4 + r;
                size_t idx = (size_t)row * NS + col;
                float v = acc[ct][r] + bbv;
                if (HAS_RES) v += res[(size_t)row * 256 + col];
                if (OUT_BF16) outB[idx] = (bf16)v;
                else          outF[idx] = v;
            }
        }
#pragma unroll
        for (int i = 0; i < 8; ++i) curH[i] = nxtH[i];
    }
}

static __device__ __forceinline__ void b8f(uint4 u, float* f) {
    f[0] = __uint_as_float(u.x << 16); f[1] = __uint_as_float(u.x & 0xffff0000u);
    f[2] = __uint_as_float(u.y << 16); f[3] = __uint_as_float(u.y & 0xffff0000u);
    f[4] = __uint_as_float(u.z << 16); f[5] = __uint_as_float(u.z & 0xffff0000u);
    f[6] = __uint_as_float(u.w << 16); f[7] = __uint_as_float(u.w & 0xffff0000u);
}

// Deformable sampling v2 (x-pair gathers): ONE WAVE per (query,head).
// lane = (ps=lane>>3: point-in-set, dg8=lane&7: 16B chunk of the 128B x-pair).
// Two passes cover 16 points. Pair base px0=clamp(x0,0,W-2); per-half weight
// picks wx0/wx1/0 so zero-padding semantics match the reference.
__global__ __launch_bounds__(256) void sample4_k(
    const bf16* __restrict__ vv, const float* __restrict__ comb,
    const float* __restrict__ refp, const float* __restrict__ lref,
    bf16* __restrict__ outb)
{
    const int cH[4] = {92, 46, 23, 12};
    const int cW[4] = {160, 80, 40, 20};
    const int cS[4] = {0, 14720, 18400, 19320};
    const int w = threadIdx.x >> 6;
    const int lane = threadIdx.x & 63;
    const int wid = blockIdx.x * 4 + w;        // (bq, h)
    const int bq = wid >> 3, h = wid & 7;
    const int b = bq / NQ;
    const int ps = lane >> 3;                  // point within set (0..7)
    const int dg8 = lane & 7;                  // 16B chunk in 128B pair
    const int hx2 = dg8 >> 2;                  // which pixel of the pair

    float lg0 = comb[(size_t)bq * 384 + 256 + h * 16 + ps];
    float lg1 = comb[(size_t)bq * 384 + 256 + h * 16 + 8 + ps];
    float mx = fmaxf(lg0, lg1);
#pragma unroll
    for (int s = 8; s < 64; s <<= 1) mx = fmaxf(mx, __shfl_xor(mx, s));
    float e0 = __expf(lg0 - mx), e1 = __expf(lg1 - mx);
    float ss = e0 + e1;
#pragma unroll
    for (int s = 8; s < 64; s <<= 1) ss += __shfl_xor(ss, s);
    float inv = 1.f / ss;

    float acc[8];
#pragma unroll
    for (int j = 0; j < 8; j++) acc[j] = 0.f;

    const float* rp = refp + (size_t)bq * 8;
    float lrx = lref[(size_t)bq * 16 + h * 2];
    float lry = lref[(size_t)bq * 16 + h * 2 + 1];

#pragma unroll
    for (int s2 = 0; s2 < 2; ++s2) {
        int p = s2 * 8 + ps;
        int lvl = p >> 2;
        const int Hh = cH[lvl], Ww = cW[lvl];
        float ox = comb[(size_t)bq * 384 + h * 32 + p * 2];
        float oy = comb[(size_t)bq * 384 + h * 32 + p * 2 + 1];
        float rx = rp[lvl * 2], ry = rp[lvl * 2 + 1];

        float px = (rx + ox / (float)Ww + lrx) * (float)Ww - 0.5f;
        float py = (ry + oy / (float)Hh + lry) * (float)Hh - 0.5f;
        float x0f = floorf(px), y0f = floorf(py);
        int x0 = (int)x0f, y0 = (int)y0f;
        float wx1 = px - x0f, wx0 = 1.f - wx1;
        float wy1 = py - y0f, wy0 = 1.f - wy1;
        bool xa = (unsigned)x0 < (unsigned)Ww, xb = (unsigned)(x0 + 1) < (unsigned)Ww;
        bool ya = (unsigned)y0 < (unsigned)Hh, yb = (unsigned)(y0 + 1) < (unsigned)Hh;
        int px0 = min(max(x0, 0), Ww - 2);
        int hx = px0 + hx2;                     // the pixel this lane-half holds
        float wxh = (hx == x0 && xa) ? wx0 : ((hx == x0 + 1 && xb) ? wx1 : 0.f);
        int yc0 = min(max(y0, 0), Hh - 1), yc1 = min(max(y0 + 1, 0), Hh - 1);
        float wgt = (s2 ? e1 : e0) * inv;
        float wA = wgt * wy0 * (ya ? 1.f : 0.f) * wxh;
        float wB = wgt * wy1 * (yb ? 1.f : 0.f) * wxh;

        const bf16* base = vv + ((size_t)(b * 8 + h) * NVP + cS[lvl]) * 32 + dg8 * 8;
        uint4 gA = *(const uint4*)(base + ((size_t)yc0 * Ww + px0) * 32);
        uint4 gB = *(const uint4*)(base + ((size_t)yc1 * Ww + px0) * 32);

        float f[8];
        b8f(gA, f);
#pragma unroll
        for (int j = 0; j < 8; j++) acc[j] = fmaf(wA, f[j], acc[j]);
        b8f(gB, f);
#pragma unroll
        for (int j = 0; j < 8; j++) acc[j] = fmaf(wB, f[j], acc[j]);
    }

#pragma unroll
    for (int s = 4; s < 64; s <<= 1)
#pragma unroll
        for (int j = 0; j < 8; j++) acc[j] += __shfl_xor(acc[j], s);

    if (lane < 4) {
        bf16x8 o;
#pragma unroll
        for (int j = 0; j < 8; j++) o[j] = (bf16)acc[j];
        *(bf16x8*)(outb + (size_t)bq * 256 + h * 32 + lane * 8) = o;
    }
}

extern "C" void kernel_launch(void* const* d_in, const int* in_sizes, int n_in,
                              void* d_out, int out_size, void* d_ws, size_t ws_size,
                              hipStream_t stream) {
    (void)in_sizes; (void)n_in; (void)out_size; (void)ws_size;
    const float* query = (const float*)d_in[0];
    const float* value = (const float*)d_in[1];
    const float* qpos  = (const float*)d_in[2];
    const float* refp  = (const float*)d_in[3];
    const float* lref  = (const float*)d_in[4];
    const float* Wv   = (const float*)d_in[6];
    const float* bv   = (const float*)d_in[7];
    const float* Wo   = (const float*)d_in[8];
    const float* bo   = (const float*)d_in[9];
    const float* Wa   = (const float*)d_in[10];
    const float* ba   = (const float*)d_in[11];
    const float* Wout = (const float*)d_in[12];
    const float* bout = (const float*)d_in[13];

    char* ws = (char*)d_ws;
    bf16*  Wv_p   = (bf16*)(ws + 0);          //   131,072
    bf16*  Wo_p   = (bf16*)(ws + 131072);     //   131,072  (Wo_p||Wa_p = packed [384][256])
    bf16*  Wa_p   = (bf16*)(ws + 262144);     //    65,536
    bf16*  Wout_p = (bf16*)(ws + 327680);     //   131,072
    bf16*  qsum   = (bf16*)(ws + 458752);     // 4,915,200
    float* comb   = (float*)(ws + 5373952);   // 14,745,600 (off|attn fused, [9600][384])
    bf16*  tsa_b  = (bf16*)(ws + 20119552);   // 4,915,200
    bf16*  v_b    = (bf16*)(ws + 25034752);   // 80,216,064 ([b][h][NVP][32], padded)
    float* cbias  = (float*)(ws + 105250816); //      1,536

    prep_k<<<1257, 256, 0, stream>>>(Wv, Wo, Wa, Wout, query, qpos, bo, ba,
                                     Wv_p, Wo_p, Wa_p, Wout_p, qsum, cbias);

    // v[b][h][pix][32] = value @ Wv + bv (bf16): 1224 128-row tiles, 1 per block
    vgemm_k<<<BS * TPB, 256, 0, stream>>>(value, Wv_p, bv, v_b);
    // comb = qsum @ [Wo|Wa] + [bo|ba] (f32, N=384): 3 col groups x 150 tiles
    gemm3_k<384, 128, 3, false, false><<<450, 256, 0, stream>>>(
        qsum, Wo_p, cbias, nullptr, comb, nullptr, (BS * NQ) / 64);
    // deformable sampling -> tsa (bf16): one wave per (q,h), x-pair gathers
    sample4_k<<<(BS * NQ * 8) / 4, 256, 0, stream>>>(v_b, comb, refp, lref, tsa_b);
    // out = tsa @ Wout + bout + query (f32)
    gemm3_k<256, 128, 2, true, false><<<300, 256, 0, stream>>>(
        tsa_b, Wout_p, bout, query, (float*)d_out, nullptr, (BS * NQ) / 64);
}